// Round 8
// baseline (477.924 us; speedup 1.0000x reference)
//
#include <hip/hip_runtime.h>
#include <stdint.h>
#include <stddef.h>

typedef __attribute__((ext_vector_type(8))) short short8;
typedef __attribute__((ext_vector_type(4))) float floatx4;
typedef __attribute__((ext_vector_type(2))) float floatx2;
typedef __attribute__((ext_vector_type(2))) unsigned int uintx2;
typedef __attribute__((ext_vector_type(4))) unsigned int uintx4;
typedef __attribute__((ext_vector_type(4))) int intx4;

#define HW_IN   4096       // 64*64
#define HW_GO   3844       // 62*62
#define OUT_ELEMS 294912   // 256*128*9
#define NCHUNK 64          // (n, half-of-i): z = n*2 + half
#define UNITS  31

// ws layout (bytes):
//   [0, 75497472)          : fp32 partials, 64 chunks x OUT_ELEMS
//   [75497472, 140509184)  : GO_ws bf16 [n][i][o=256][64] LINEAR,
//                            cols 62,63 zero (K padding)
//   [140509184, 174063616) : X_ws bf16 [n][c=128][h=64][w=64] LINEAR
#define PART_BYTES   75497472ull
#define GO_BYTES     65011712ull
#define X_BYTES      33554432ull
#define WS_FULL      (PART_BYTES + GO_BYTES + X_BYTES)
#define PART62_BYTES 73138176ull   // fallback: 62-chunk fp32 partials

#define GO_THREADS 1015808u   // 4,063,232 GO chunk-tasks / 4
#define GO_BLOCKS  3968
#define X_THREADS  524288u    // 2,097,152 X chunk-tasks / 4
#define X_BLOCKS   2048

__device__ __forceinline__ uint32_t pk_bf16(float a, float b) {
    uint32_t ua = __float_as_uint(a); ua += 0x7FFFu + ((ua >> 16) & 1u);
    uint32_t ub = __float_as_uint(b); ub += 0x7FFFu + ((ub >> 16) & 1u);
    return (ua >> 16) | (ub & 0xFFFF0000u);
}

// ---- prep: both fp32->bf16 conversions, LINEAR layouts (no swizzle) ----
__global__ __launch_bounds__(256) void prep_kernel(
    const float* __restrict__ gout, const float* __restrict__ inp,
    uintx4* __restrict__ go_ws4, uintx4* __restrict__ x_ws4)
{
    const uint32_t b = blockIdx.x;
    if (b < GO_BLOCKS) {
        const uint32_t t0 = b * 256u + threadIdx.x;
#pragma unroll
        for (int it = 0; it < 4; ++it) {
            const uint32_t g = t0 + (uint32_t)it * GO_THREADS;
            const uint32_t row = g >> 3, q = g & 7u;   // row=(n*62+i)*256+o
            const uint32_t o = row & 255u, nio = row >> 8;
            const uint32_t n = nio / 62u, i = nio - n * 62u;
            const float* s = gout + (size_t)(n * 256u + o) * HW_GO
                                  + i * 62u + q * 8u;
            const floatx2 a0 = *(const floatx2*)(s);
            const floatx2 a1 = *(const floatx2*)(s + 2);
            const floatx2 a2 = *(const floatx2*)(s + 4);
            uintx4 v;
            v.x = pk_bf16(a0.x, a0.y);
            v.y = pk_bf16(a1.x, a1.y);
            v.z = pk_bf16(a2.x, a2.y);
            if (q < 7u) {                 // cols 62,63 stay zero (K padding)
                const floatx2 a3 = *(const floatx2*)(s + 6);
                v.w = pk_bf16(a3.x, a3.y);
            } else v.w = 0u;
            go_ws4[(size_t)row * 8u + q] = v;
        }
    } else {
        const uint32_t t0 = (b - GO_BLOCKS) * 256u + threadIdx.x;
        const floatx4* inp4 = (const floatx4*)inp;
#pragma unroll
        for (int it = 0; it < 4; ++it) {
            const uint32_t t2 = t0 + (uint32_t)it * X_THREADS;
            const floatx4 v0 = inp4[(size_t)t2 * 2];
            const floatx4 v1 = inp4[(size_t)t2 * 2 + 1];
            uintx4 w;
            w.x = pk_bf16(v0.x, v0.y); w.y = pk_bf16(v0.z, v0.w);
            w.z = pk_bf16(v1.x, v1.y); w.w = pk_bf16(v1.z, v1.w);
            x_ws4[t2] = w;
        }
    }
}

// ---- main GEMM: ZERO LDS, ZERO barriers. 4 independent waves/block,
//      wave = 32o x 32c; A and B fragments loaded per-lane from staged
//      bf16 buffers (L2-resident via XCD z-clustering). ----
__global__ __launch_bounds__(256, 2) void convbw3_kernel(
    const short* __restrict__ go_ws,   // [n][i][256][64] bf16 linear
    const short* __restrict__ x_ws,    // [n][128][64][64] bf16 linear
    float* __restrict__ part)          // partials, chunk-major
{
    const int tid  = threadIdx.x;
    const int lane = tid & 63;
    const int wave = tid >> 6;
    const int l15  = lane & 15;
    const int quad = lane >> 4;

    // XCD swizzle: ids round-robin the 8 XCDs; give each XCD 64
    // consecutive sw -> 8 z-chunks co-located for GO/X L2 reuse (R4).
    const uint32_t bid = (blockIdx.z * 4 + blockIdx.y) * 2 + blockIdx.x;
    const uint32_t sw  = (bid & 7u) * 64u + (bid >> 3);   // 512 = 8*64
    const int xs = sw & 1;
    const int ys = (sw >> 1) & 3;
    const int zs = sw >> 3;

    const int Mbase = xs * 128;        // 0,128
    const int Cbase = ys * 32;         // 0..96
    const int nimg  = zs >> 1;         // image
    const int i0    = (zs & 1) * 31;   // i in [i0, i0+31)

    // A rows: o = Mbase + wave*32 + mi*16 + l15, K-chunk quad
    const short* a_row = go_ws + ((size_t)(nimg * 62) << 14)
                       + ((Mbase + wave * 32 + l15) << 6) + (quad << 3);
    // X rows: c = Cbase + ni*16 + l15
    const short* x_c0 = x_ws + ((size_t)(nimg * 128 + Cbase + l15) << 12);
    const short* x_c1 = x_c0 + ((size_t)16 << 12);

    floatx4 acc[2][2][9];
#pragma unroll
    for (int mi = 0; mi < 2; ++mi)
#pragma unroll
        for (int ni = 0; ni < 2; ++ni)
#pragma unroll
            for (int t = 0; t < 9; ++t)
                acc[mi][ni][t] = (floatx4){0.f, 0.f, 0.f, 0.f};

#pragma unroll 1
    for (int uu = 0; uu < UNITS; ++uu) {
        const int i = i0 + uu;

        // A fragments for this unit (4 x b128, per-lane, 16B-aligned)
        const short* ab = a_row + ((size_t)i << 14);
        short8 a[2][2];
#pragma unroll
        for (int mi = 0; mi < 2; ++mi)
#pragma unroll
            for (int ks = 0; ks < 2; ++ks)
                a[mi][ks] = *(const short8*)(ab + (mi << 10) + (ks << 5));

#pragma unroll
        for (int kh = 0; kh < 3; ++kh) {
            const int h = i + kh;              // <= 63, always valid
#pragma unroll
            for (int ni = 0; ni < 2; ++ni) {
                const short* xrow = (ni ? x_c1 : x_c0) + (h << 6);
#pragma unroll
                for (int ks = 0; ks < 2; ++ks) {
                    const int lc = ks * 4 + quad;
                    const intx4 d = *(const intx4*)(xrow + (lc << 3));
                    // next chunk's first dword; lc=7 wraps to chunk 0 of the
                    // same row (valid mem, garbage) -> multiplied by zero A
                    // K-cols 62,63. Same contract as all passing rounds.
                    const int d4 =
                        *(const int*)(xrow + ((((lc + 1) & 7)) << 3));
                    const uint32_t e0 = (uint32_t)d.x, e1 = (uint32_t)d.y,
                                   e2 = (uint32_t)d.z, e3 = (uint32_t)d.w,
                                   e4 = (uint32_t)d4;
                    union { uint32_t u[4]; short8 s; } f0, f1, f2;
                    f0.u[0] = e0; f0.u[1] = e1; f0.u[2] = e2; f0.u[3] = e3;
                    // f1 dword k = e_k>>16 | e_{k+1}<<16 == v_perm_b32
                    f1.u[0] = __builtin_amdgcn_perm(e1, e0, 0x05040302u);
                    f1.u[1] = __builtin_amdgcn_perm(e2, e1, 0x05040302u);
                    f1.u[2] = __builtin_amdgcn_perm(e3, e2, 0x05040302u);
                    f1.u[3] = __builtin_amdgcn_perm(e4, e3, 0x05040302u);
                    f2.u[0] = e1; f2.u[1] = e2; f2.u[2] = e3; f2.u[3] = e4;
#pragma unroll
                    for (int mi = 0; mi < 2; ++mi) {
                        acc[mi][ni][kh * 3 + 0] =
                            __builtin_amdgcn_mfma_f32_16x16x32_bf16(
                                a[mi][ks], f0.s, acc[mi][ni][kh * 3 + 0], 0, 0, 0);
                        acc[mi][ni][kh * 3 + 1] =
                            __builtin_amdgcn_mfma_f32_16x16x32_bf16(
                                a[mi][ks], f1.s, acc[mi][ni][kh * 3 + 1], 0, 0, 0);
                        acc[mi][ni][kh * 3 + 2] =
                            __builtin_amdgcn_mfma_f32_16x16x32_bf16(
                                a[mi][ks], f2.s, acc[mi][ni][kh * 3 + 2], 0, 0, 0);
                    }
                }
            }
        }
    }

    // epilogue: C/D layout col=lane&15, row=quad*4+reg (m89/m91)
    float* baseo = part + (size_t)zs * OUT_ELEMS;
#pragma unroll
    for (int mi = 0; mi < 2; ++mi) {
        const int o_base = Mbase + wave * 32 + mi * 16 + quad * 4;
#pragma unroll
        for (int ni = 0; ni < 2; ++ni) {
            const int c = Cbase + ni * 16 + l15;
#pragma unroll
            for (int t = 0; t < 9; ++t)
#pragma unroll
                for (int r = 0; r < 4; ++r)
                    baseo[(size_t)(o_base + r) * 1152 + c * 9 + t] =
                        acc[mi][ni][t][r];
        }
    }
}

__global__ __launch_bounds__(256) void reduce_kernel(
    const floatx4* __restrict__ ws, floatx4* __restrict__ out, int nchunk)
{
    const int idx = blockIdx.x * 256 + threadIdx.x;
    floatx4 s = {0.f, 0.f, 0.f, 0.f};
#pragma unroll 4
    for (int ch = 0; ch < nchunk; ++ch)
        s += ws[(size_t)ch * (OUT_ELEMS / 4) + idx];
    out[idx] = s;
}

// ================= fallback (fp32 direct, self-contained) =================
template<bool USE_ATOMIC>
__global__ __launch_bounds__(256, 1) void convbw_kernel(
    const float* __restrict__ inp, const float* __restrict__ gout,
    float* __restrict__ dst)
{
    __shared__ __align__(16) short GO_sh[128][72];
    __shared__ __align__(16) short X_sh[3][3][32][72];
    const int tid = threadIdx.x, lane = tid & 63, wave = tid >> 6;
    const int l15 = lane & 15, quad = lane >> 4;
    const int Mbase = blockIdx.x * 128, Cbase = blockIdx.y * 32;
    const int chunk = blockIdx.z;
    const int gl = tid & 31, grow0 = tid >> 5, xl = tid & 15, xrow0 = tid >> 4;
    floatx2 go_r[16];
    floatx4 x_r[6];
    auto issue_loads = [&](int u) {
        const int n_img = u / 62, i = u - n_img * 62;
        const float* bg = gout + (size_t)(n_img * 256 + Mbase) * HW_GO + i * 62;
        const float* bi = inp + (size_t)(n_img * 128 + Cbase) * HW_IN + i * 64;
#pragma unroll
        for (int p = 0; p < 16; ++p)
            go_r[p] = *(const floatx2*)(bg + (size_t)(grow0 + p * 8) * HW_GO + gl * 2);
#pragma unroll
        for (int p = 0; p < 6; ++p) {
            const int row = xrow0 + p * 16, c = row & 31, kh = row >> 5;
            x_r[p] = *(const floatx4*)(bi + (size_t)c * HW_IN + kh * 64 + xl * 4);
        }
    };
    auto flush = [&]() {
#pragma unroll
        for (int p = 0; p < 16; ++p) {
            uint32_t v = pk_bf16(go_r[p].x, go_r[p].y);
            if (gl == 31) v = 0;
            *(uint32_t*)&GO_sh[grow0 + p * 8][gl * 2] = v;
        }
#pragma unroll
        for (int p = 0; p < 6; ++p) {
            const int row = xrow0 + p * 16, c = row & 31, kh = row >> 5;
            uint32_t lo = pk_bf16(x_r[p].x, x_r[p].y);
            uint32_t hi = pk_bf16(x_r[p].z, x_r[p].w);
            uint32_t nlo = (uint32_t)__shfl((int)lo, (lane + 1) & 63);
            uintx2 v0 = {lo, hi};
            uintx2 v1 = {(lo >> 16) | (hi << 16), (hi >> 16) | (nlo << 16)};
            uintx2 v2 = {hi, nlo};
            *(uintx2*)&X_sh[kh][0][c][xl * 4] = v0;
            *(uintx2*)&X_sh[kh][1][c][xl * 4] = v1;
            *(uintx2*)&X_sh[kh][2][c][xl * 4] = v2;
        }
    };
    floatx4 acc[2][2][9];
#pragma unroll
    for (int mi = 0; mi < 2; ++mi)
#pragma unroll
        for (int ni = 0; ni < 2; ++ni)
#pragma unroll
            for (int t = 0; t < 9; ++t) acc[mi][ni][t] = (floatx4){0,0,0,0};
    issue_loads(chunk * 32);
#pragma unroll 1
    for (int uu = 0; uu < 32; ++uu) {
        flush();
        if (uu + 1 < 32) issue_loads(chunk * 32 + uu + 1);
        __syncthreads();
#pragma unroll
        for (int ks = 0; ks < 2; ++ks) {
            const int kc = ks * 32 + quad * 8;
            const short8 a0 = *(const short8*)&GO_sh[wave * 32 + l15][kc];
            const short8 a1 = *(const short8*)&GO_sh[wave * 32 + 16 + l15][kc];
#pragma unroll
            for (int kh = 0; kh < 3; ++kh)
#pragma unroll
                for (int kw = 0; kw < 3; ++kw) {
                    const int t = kh * 3 + kw;
#pragma unroll
                    for (int ni = 0; ni < 2; ++ni) {
                        const short8 b = *(const short8*)&X_sh[kh][kw][ni * 16 + l15][kc];
                        acc[0][ni][t] = __builtin_amdgcn_mfma_f32_16x16x32_bf16(a0, b, acc[0][ni][t], 0, 0, 0);
                        acc[1][ni][t] = __builtin_amdgcn_mfma_f32_16x16x32_bf16(a1, b, acc[1][ni][t], 0, 0, 0);
                    }
                }
        }
        __syncthreads();
    }
    float* base = USE_ATOMIC ? dst : dst + (size_t)chunk * OUT_ELEMS;
#pragma unroll
    for (int mi = 0; mi < 2; ++mi) {
        const int o_base = Mbase + wave * 32 + mi * 16 + quad * 4;
#pragma unroll
        for (int ni = 0; ni < 2; ++ni) {
            const int c = Cbase + ni * 16 + l15;
#pragma unroll
            for (int t = 0; t < 9; ++t)
#pragma unroll
                for (int r = 0; r < 4; ++r) {
                    const size_t off = (size_t)(o_base + r) * 1152 + c * 9 + t;
                    if (USE_ATOMIC) atomicAdd(base + off, acc[mi][ni][t][r]);
                    else base[off] = acc[mi][ni][t][r];
                }
        }
    }
}

extern "C" void kernel_launch(void* const* d_in, const int* in_sizes, int n_in,
                              void* d_out, int out_size, void* d_ws, size_t ws_size,
                              hipStream_t stream) {
    const float* inp  = (const float*)d_in[0];
    const float* gout = (const float*)d_in[1];

    if (ws_size >= WS_FULL) {
        float* part = (float*)d_ws;
        uintx4* go_ws4 = (uintx4*)((char*)d_ws + PART_BYTES);
        uintx4* x_ws4  = (uintx4*)((char*)d_ws + PART_BYTES + GO_BYTES);
        prep_kernel<<<GO_BLOCKS + X_BLOCKS, 256, 0, stream>>>(
            gout, inp, go_ws4, x_ws4);
        convbw3_kernel<<<dim3(2, 4, NCHUNK), 256, 0, stream>>>(
            (const short*)go_ws4, (const short*)x_ws4, part);
        reduce_kernel<<<OUT_ELEMS / 4 / 256, 256, 0, stream>>>(
            (const floatx4*)part, (floatx4*)d_out, NCHUNK);
        return;
    }
    // fallback: fp32-direct path (no bf16 staging buffers needed)
    dim3 grid(2, 4, 62);
    if (ws_size >= PART62_BYTES) {
        float* part = (float*)d_ws;
        convbw_kernel<false><<<grid, 256, 0, stream>>>(inp, gout, part);
        reduce_kernel<<<OUT_ELEMS / 4 / 256, 256, 0, stream>>>(
            (const floatx4*)part, (floatx4*)d_out, 62);
    } else {
        hipMemsetAsync(d_out, 0, (size_t)out_size * sizeof(float), stream);
        convbw_kernel<true><<<grid, 256, 0, stream>>>(inp, gout, (float*)d_out);
    }
}

// Round 9
// 303.515 us; speedup vs baseline: 1.5746x; 1.5746x over previous
//
#include <hip/hip_runtime.h>
#include <stdint.h>
#include <stddef.h>

typedef __attribute__((ext_vector_type(8))) short short8;
typedef __attribute__((ext_vector_type(4))) float floatx4;
typedef __attribute__((ext_vector_type(2))) float floatx2;
typedef __attribute__((ext_vector_type(2))) unsigned int uintx2;
typedef __attribute__((ext_vector_type(4))) unsigned int uintx4;
typedef __attribute__((ext_vector_type(4))) int intx4;

#define HW_IN   4096       // 64*64
#define HW_GO   3844       // 62*62
#define OUT_ELEMS 294912   // 256*128*9
#define NCHUNK 64          // (n, half-of-i): z = n*2 + half
#define UNITS  31

// ws layout (bytes):
//   [0, 75497472)          : fp32 partials, 64 chunks x OUT_ELEMS
//   [75497472, 140509184)  : GO_ws bf16 [n][i][o=256][64], 16B chunks
//                            XOR-swizzled within each 128B row by (o&7),
//                            cols 62,63 zero
// (X staging folded into the GEMM: input fp32 converted in-kernel)
#define PART_BYTES   75497472ull
#define GO_BYTES     65011712ull
#define WS_MAIN      (PART_BYTES + GO_BYTES)
#define PART62_BYTES 73138176ull   // fallback: 62-chunk fp32 partials

#define GO_THREADS 1015808u   // 4,063,232 GO chunk-tasks / 4
#define GO_BLOCKS  3968

__device__ __forceinline__ uint32_t pk_bf16(float a, float b) {
    uint32_t ua = __float_as_uint(a); ua += 0x7FFFu + ((ua >> 16) & 1u);
    uint32_t ub = __float_as_uint(b); ub += 0x7FFFu + ((ub >> 16) & 1u);
    return (ua >> 16) | (ub & 0xFFFF0000u);
}

__device__ __forceinline__ void load_lds16(const void* g, void* l) {
    // LDS dest = wave-uniform base + lane*16 (m104/m108); global side per-lane.
    __builtin_amdgcn_global_load_lds(
        (const __attribute__((address_space(1))) void*)g,
        (__attribute__((address_space(3))) void*)l, 16, 0, 0);
}

// ---- prep: gout fp32 -> GO_ws bf16 (o&7 XOR-swizzled 16B chunks) ----
__global__ __launch_bounds__(256) void prep_go(
    const float* __restrict__ gout, uintx4* __restrict__ go_ws4)
{
    const uint32_t t0 = blockIdx.x * 256u + threadIdx.x;
#pragma unroll
    for (int it = 0; it < 4; ++it) {
        const uint32_t g = t0 + (uint32_t)it * GO_THREADS;
        const uint32_t row = g >> 3, q = g & 7u;   // row=(n*62+i)*256+o
        const uint32_t o = row & 255u, nio = row >> 8;
        const uint32_t n = nio / 62u, i = nio - n * 62u;
        const float* s = gout + (size_t)(n * 256u + o) * HW_GO
                              + i * 62u + q * 8u;
        const floatx2 a0 = *(const floatx2*)(s);
        const floatx2 a1 = *(const floatx2*)(s + 2);
        const floatx2 a2 = *(const floatx2*)(s + 4);
        uintx4 v;
        v.x = pk_bf16(a0.x, a0.y);
        v.y = pk_bf16(a1.x, a1.y);
        v.z = pk_bf16(a2.x, a2.y);
        if (q < 7u) {                 // cols 62,63 stay zero (K padding)
            const floatx2 a3 = *(const floatx2*)(s + 6);
            v.w = pk_bf16(a3.x, a3.y);
        } else v.w = 0u;
        go_ws4[(size_t)row * 8u + (q ^ (o & 7u))] = v;
    }
}

// ---- main GEMM: R2-proven skeleton (GO 2-buf DMA + X 4-ring, 1-ahead,
//      plain __syncthreads) with X staged IN-KERNEL from fp32 input:
//      per lane 8 fp32 -> pk -> ds_write_b128, swizzled (l&7)^(l>>3). ----
__global__ __launch_bounds__(256, 2) void convbw3_kernel(
    const float* __restrict__ inp,     // fp32 [n][128][64][64]
    const short* __restrict__ go_ws,   // [n][i][256][64] bf16, swizzled
    float* __restrict__ part)          // partials, chunk-major
{
    __shared__ __align__(16) short GO_sh[2][128 * 64];  // 32768 B
    __shared__ __align__(16) short X_ring[4][32 * 64];  // 16384 B (48KB)

    const int tid  = threadIdx.x;
    const int lane = tid & 63;
    const int wave = tid >> 6;
    const int l15  = lane & 15;
    const int quad = lane >> 4;

    // XCD swizzle (R4-proven): ids round-robin the 8 XCDs; each XCD gets
    // 64 consecutive sw -> 8 z-chunks (4 images) co-located for L2 reuse.
    const uint32_t bid = (blockIdx.z * 4 + blockIdx.y) * 2 + blockIdx.x;
    const uint32_t sw  = (bid & 7u) * 64u + (bid >> 3);   // 512 = 8*64
    const int xs = sw & 1;
    const int ys = (sw >> 1) & 3;
    const int zs = sw >> 3;

    const int Mbase = xs * 128;        // 0,128
    const int Cbase = ys * 32;         // 0..96
    const int nimg  = zs >> 1;         // image
    const int i0    = (zs & 1) * 31;   // i in [i0, i0+31)

    const short* go_b = go_ws + ((size_t)(nimg * 62) << 14);
    const int glane_off = lane << 3;

    auto issue_go = [&](int u, int buf) {   // 4 loads/wave
        const short* gsrc = go_b + ((size_t)(i0 + u) << 14) + (Mbase << 6);
        short* gdst = &GO_sh[buf][0];
#pragma unroll
        for (int k = wave; k < 16; k += 4)
            load_lds16(gsrc + k * 512 + glane_off, gdst + k * 512);
    };

    // X staging: lane handles row r = wave*8 + (lane>>3), cols (lane&7)*8..+7
    const int xrow_loc = wave * 8 + (lane >> 3);          // 0..31
    const float* x_src = inp + ((size_t)(nimg * 128 + Cbase + xrow_loc) << 12)
                             + ((lane & 7) << 3);
    // swizzled LDS byte position within a slot (matches read-side ^r7)
    short* x_dst = &X_ring[0][0] + xrow_loc * 64
                 + (((lane & 7) ^ (lane >> 3)) << 3);

    floatx4 xf0, xf1;                 // staged fp32 (row h, 8 floats)
    auto load_xf = [&](int h) {       // coalesced: 8 lanes cover a 64-f row
        if (h < 64) {
            xf0 = *(const floatx4*)(x_src + (h << 6));
            xf1 = *(const floatx4*)(x_src + (h << 6) + 4);
        }
    };
    uintx4 xp;                        // packed bf16, carried across barrier
    auto pack_xf = [&]() {
        xp.x = pk_bf16(xf0.x, xf0.y); xp.y = pk_bf16(xf0.z, xf0.w);
        xp.z = pk_bf16(xf1.x, xf1.y); xp.w = pk_bf16(xf1.z, xf1.w);
    };
    auto write_x = [&](int h) {       // ds_write_b128 into slot h&3
        if (h < 64)
            *(uintx4*)(x_dst + ((h & 3) << 11)) = xp;   // 2048 shorts/slot
    };

    floatx4 acc[2][2][9];
#pragma unroll
    for (int mi = 0; mi < 2; ++mi)
#pragma unroll
        for (int ni = 0; ni < 2; ++ni)
#pragma unroll
            for (int t = 0; t < 9; ++t)
                acc[mi][ni][t] = (floatx4){0.f, 0.f, 0.f, 0.f};

    // prologue: fill X slots i0..i0+2, stage XF(i0+3), GO(0) in flight
#pragma unroll
    for (int m = 0; m < 3; ++m) {
        load_xf(i0 + m); pack_xf(); write_x(i0 + m);
    }
    load_xf(i0 + 3); pack_xf();
    issue_go(0, 0);

    const int r7 = l15 & 7;
#pragma unroll 1
    for (int uu = 0; uu < UNITS; ++uu) {
        const int i = i0 + uu;
        __syncthreads();   // drains GO DMA + XF loads issued last phase

        write_x(i + 3);                      // packed last phase; slot (i-1)&3
        if (uu + 1 < UNITS) issue_go(uu + 1, (uu + 1) & 1);
        load_xf(i + 4);                      // completes under compute

        const short* Gb = &GO_sh[uu & 1][0];
        short8 a[2][2];
#pragma unroll
        for (int mi = 0; mi < 2; ++mi)
#pragma unroll
            for (int ks = 0; ks < 2; ++ks)
                a[mi][ks] = *(const short8*)(
                    Gb + ((wave * 32 + mi * 16 + l15) << 6)
                       + ((((ks << 2) | quad) ^ r7) << 3));

#pragma unroll
        for (int kh = 0; kh < 3; ++kh) {
            const short* Xs = &X_ring[(i + kh) & 3][0];
#pragma unroll
            for (int ni = 0; ni < 2; ++ni) {
                const short* xrow = Xs + ((ni * 16 + l15) << 6);
#pragma unroll
                for (int ks = 0; ks < 2; ++ks) {
                    const int lc = ks * 4 + quad;
                    const intx4 d = *(const intx4*)(xrow + ((lc ^ r7) << 3));
                    const int d4 =
                        *(const int*)(xrow + ((((lc + 1) & 7) ^ r7) << 3));
                    const uint32_t e0 = (uint32_t)d.x, e1 = (uint32_t)d.y,
                                   e2 = (uint32_t)d.z, e3 = (uint32_t)d.w,
                                   e4 = (uint32_t)d4;
                    union { uint32_t u[4]; short8 s; } f0, f1, f2;
                    f0.u[0] = e0; f0.u[1] = e1; f0.u[2] = e2; f0.u[3] = e3;
                    // f1 dword k = e_k>>16 | e_{k+1}<<16 == v_perm_b32
                    f1.u[0] = __builtin_amdgcn_perm(e1, e0, 0x05040302u);
                    f1.u[1] = __builtin_amdgcn_perm(e2, e1, 0x05040302u);
                    f1.u[2] = __builtin_amdgcn_perm(e3, e2, 0x05040302u);
                    f1.u[3] = __builtin_amdgcn_perm(e4, e3, 0x05040302u);
                    f2.u[0] = e1; f2.u[1] = e2; f2.u[2] = e3; f2.u[3] = e4;
#pragma unroll
                    for (int mi = 0; mi < 2; ++mi) {
                        acc[mi][ni][kh * 3 + 0] =
                            __builtin_amdgcn_mfma_f32_16x16x32_bf16(
                                a[mi][ks], f0.s, acc[mi][ni][kh * 3 + 0], 0, 0, 0);
                        acc[mi][ni][kh * 3 + 1] =
                            __builtin_amdgcn_mfma_f32_16x16x32_bf16(
                                a[mi][ks], f1.s, acc[mi][ni][kh * 3 + 1], 0, 0, 0);
                        acc[mi][ni][kh * 3 + 2] =
                            __builtin_amdgcn_mfma_f32_16x16x32_bf16(
                                a[mi][ks], f2.s, acc[mi][ni][kh * 3 + 2], 0, 0, 0);
                    }
                }
            }
        }
        pack_xf();      // loads complete by now; 4 regs across the barrier
    }

    // epilogue: C/D layout col=lane&15, row=quad*4+reg (m89/m91)
    float* baseo = part + (size_t)zs * OUT_ELEMS;
#pragma unroll
    for (int mi = 0; mi < 2; ++mi) {
        const int o_base = Mbase + wave * 32 + mi * 16 + quad * 4;
#pragma unroll
        for (int ni = 0; ni < 2; ++ni) {
            const int c = Cbase + ni * 16 + l15;
#pragma unroll
            for (int t = 0; t < 9; ++t)
#pragma unroll
                for (int r = 0; r < 4; ++r)
                    baseo[(size_t)(o_base + r) * 1152 + c * 9 + t] =
                        acc[mi][ni][t][r];
        }
    }
}

__global__ __launch_bounds__(256) void reduce_kernel(
    const floatx4* __restrict__ ws, floatx4* __restrict__ out, int nchunk)
{
    const int idx = blockIdx.x * 256 + threadIdx.x;
    floatx4 s = {0.f, 0.f, 0.f, 0.f};
#pragma unroll 4
    for (int ch = 0; ch < nchunk; ++ch)
        s += ws[(size_t)ch * (OUT_ELEMS / 4) + idx];
    out[idx] = s;
}

// ================= fallback (fp32 direct, self-contained) =================
template<bool USE_ATOMIC>
__global__ __launch_bounds__(256, 1) void convbw_kernel(
    const float* __restrict__ inp, const float* __restrict__ gout,
    float* __restrict__ dst)
{
    __shared__ __align__(16) short GO_sh[128][72];
    __shared__ __align__(16) short X_sh[3][3][32][72];
    const int tid = threadIdx.x, lane = tid & 63, wave = tid >> 6;
    const int l15 = lane & 15, quad = lane >> 4;
    const int Mbase = blockIdx.x * 128, Cbase = blockIdx.y * 32;
    const int chunk = blockIdx.z;
    const int gl = tid & 31, grow0 = tid >> 5, xl = tid & 15, xrow0 = tid >> 4;
    floatx2 go_r[16];
    floatx4 x_r[6];
    auto issue_loads = [&](int u) {
        const int n_img = u / 62, i = u - n_img * 62;
        const float* bg = gout + (size_t)(n_img * 256 + Mbase) * HW_GO + i * 62;
        const float* bi = inp + (size_t)(n_img * 128 + Cbase) * HW_IN + i * 64;
#pragma unroll
        for (int p = 0; p < 16; ++p)
            go_r[p] = *(const floatx2*)(bg + (size_t)(grow0 + p * 8) * HW_GO + gl * 2);
#pragma unroll
        for (int p = 0; p < 6; ++p) {
            const int row = xrow0 + p * 16, c = row & 31, kh = row >> 5;
            x_r[p] = *(const floatx4*)(bi + (size_t)c * HW_IN + kh * 64 + xl * 4);
        }
    };
    auto flush = [&]() {
#pragma unroll
        for (int p = 0; p < 16; ++p) {
            uint32_t v = pk_bf16(go_r[p].x, go_r[p].y);
            if (gl == 31) v = 0;
            *(uint32_t*)&GO_sh[grow0 + p * 8][gl * 2] = v;
        }
#pragma unroll
        for (int p = 0; p < 6; ++p) {
            const int row = xrow0 + p * 16, c = row & 31, kh = row >> 5;
            uint32_t lo = pk_bf16(x_r[p].x, x_r[p].y);
            uint32_t hi = pk_bf16(x_r[p].z, x_r[p].w);
            uint32_t nlo = (uint32_t)__shfl((int)lo, (lane + 1) & 63);
            uintx2 v0 = {lo, hi};
            uintx2 v1 = {(lo >> 16) | (hi << 16), (hi >> 16) | (nlo << 16)};
            uintx2 v2 = {hi, nlo};
            *(uintx2*)&X_sh[kh][0][c][xl * 4] = v0;
            *(uintx2*)&X_sh[kh][1][c][xl * 4] = v1;
            *(uintx2*)&X_sh[kh][2][c][xl * 4] = v2;
        }
    };
    floatx4 acc[2][2][9];
#pragma unroll
    for (int mi = 0; mi < 2; ++mi)
#pragma unroll
        for (int ni = 0; ni < 2; ++ni)
#pragma unroll
            for (int t = 0; t < 9; ++t) acc[mi][ni][t] = (floatx4){0,0,0,0};
    issue_loads(chunk * 32);
#pragma unroll 1
    for (int uu = 0; uu < 32; ++uu) {
        flush();
        if (uu + 1 < 32) issue_loads(chunk * 32 + uu + 1);
        __syncthreads();
#pragma unroll
        for (int ks = 0; ks < 2; ++ks) {
            const int kc = ks * 32 + quad * 8;
            const short8 a0 = *(const short8*)&GO_sh[wave * 32 + l15][kc];
            const short8 a1 = *(const short8*)&GO_sh[wave * 32 + 16 + l15][kc];
#pragma unroll
            for (int kh = 0; kh < 3; ++kh)
#pragma unroll
                for (int kw = 0; kw < 3; ++kw) {
                    const int t = kh * 3 + kw;
#pragma unroll
                    for (int ni = 0; ni < 2; ++ni) {
                        const short8 b = *(const short8*)&X_sh[kh][kw][ni * 16 + l15][kc];
                        acc[0][ni][t] = __builtin_amdgcn_mfma_f32_16x16x32_bf16(a0, b, acc[0][ni][t], 0, 0, 0);
                        acc[1][ni][t] = __builtin_amdgcn_mfma_f32_16x16x32_bf16(a1, b, acc[1][ni][t], 0, 0, 0);
                    }
                }
        }
        __syncthreads();
    }
    float* base = USE_ATOMIC ? dst : dst + (size_t)chunk * OUT_ELEMS;
#pragma unroll
    for (int mi = 0; mi < 2; ++mi) {
        const int o_base = Mbase + wave * 32 + mi * 16 + quad * 4;
#pragma unroll
        for (int ni = 0; ni < 2; ++ni) {
            const int c = Cbase + ni * 16 + l15;
#pragma unroll
            for (int t = 0; t < 9; ++t)
#pragma unroll
                for (int r = 0; r < 4; ++r) {
                    const size_t off = (size_t)(o_base + r) * 1152 + c * 9 + t;
                    if (USE_ATOMIC) atomicAdd(base + off, acc[mi][ni][t][r]);
                    else base[off] = acc[mi][ni][t][r];
                }
        }
    }
}

extern "C" void kernel_launch(void* const* d_in, const int* in_sizes, int n_in,
                              void* d_out, int out_size, void* d_ws, size_t ws_size,
                              hipStream_t stream) {
    const float* inp  = (const float*)d_in[0];
    const float* gout = (const float*)d_in[1];

    if (ws_size >= WS_MAIN) {
        float* part = (float*)d_ws;
        uintx4* go_ws4 = (uintx4*)((char*)d_ws + PART_BYTES);
        prep_go<<<GO_BLOCKS, 256, 0, stream>>>(gout, go_ws4);
        convbw3_kernel<<<dim3(2, 4, NCHUNK), 256, 0, stream>>>(
            inp, (const short*)go_ws4, part);
        reduce_kernel<<<OUT_ELEMS / 4 / 256, 256, 0, stream>>>(
            (const floatx4*)part, (floatx4*)d_out, NCHUNK);
        return;
    }
    // fallback: fp32-direct path (no bf16 staging buffers needed)
    dim3 grid(2, 4, 62);
    if (ws_size >= PART62_BYTES) {
        float* part = (float*)d_ws;
        convbw_kernel<false><<<grid, 256, 0, stream>>>(inp, gout, part);
        reduce_kernel<<<OUT_ELEMS / 4 / 256, 256, 0, stream>>>(
            (const floatx4*)part, (floatx4*)d_out, 62);
    } else {
        hipMemsetAsync(d_out, 0, (size_t)out_size * sizeof(float), stream);
        convbw_kernel<true><<<grid, 256, 0, stream>>>(inp, gout, (float*)d_out);
    }
}